// Round 13
// baseline (157.679 us; speedup 1.0000x reference)
//
#include <hip/hip_runtime.h>
#include <hip/hip_bf16.h>
#include <hip/hip_cooperative_groups.h>
#include <cstdint>

namespace cg = cooperative_groups;

typedef short  short8  __attribute__((ext_vector_type(8)));
typedef ushort ushort8 __attribute__((ext_vector_type(8)));
typedef float  f32x4   __attribute__((ext_vector_type(4)));

#define BATCH 4
#define CIN   256
#define COUT  256
#define HH    96
#define WW    96
#define HWSZ  9216
#define GN_G  16
#define EPSV  1e-5f
#define BN    144           // positions per block
#define NPB   64            // position-blocks per batch (9216/144)
#define NWG   (BATCH*NPB)   // 256 blocks = exactly 1/CU (coop co-residency), %8==0

__device__ __forceinline__ float bf2f(ushort u) {
    return __uint_as_float(((uint32_t)u) << 16);
}
__device__ __forceinline__ ushort f2bf(float f) {
    uint32_t u = __float_as_uint(f);
    u += 0x7FFFu + ((u >> 16) & 1u);   // round-to-nearest-even
    return (ushort)(u >> 16);
}

// ---- x: [b][c][p] fp32 -> xn: [b][p][c] bf16 (tiled transpose via LDS)
__global__ __launch_bounds__(256)
void nhwc_kernel(const float* __restrict__ x, ushort* __restrict__ xn) {
    __shared__ ushort tile[64][66];
    const int b  = blockIdx.z;
    const int cb = blockIdx.y * 64;
    const int pb = blockIdx.x * 64;
    const int t  = threadIdx.x;
    {
        const int pl = t & 63;
        const int cq = t >> 6;
        #pragma unroll
        for (int i = 0; i < 16; ++i) {
            const int c = cq * 16 + i;
            tile[c][pl] = f2bf(x[((size_t)b * CIN + cb + c) * HWSZ + pb + pl]);
        }
    }
    __syncthreads();
    {
        const int cl = t & 63;
        const int pq = t >> 6;
        #pragma unroll
        for (int i = 0; i < 16; ++i) {
            const int p = pq * 16 + i;
            xn[((size_t)b * HWSZ + pb + p) * CIN + cb + cl] = tile[cl][p];
        }
    }
}

// ---- weight [cout][cin][3][3] fp32 -> Wp[kb8][cout][8] bf16, globalK = tap*256 + cin
__global__ __launch_bounds__(256)
void repack_w_kernel(const float* __restrict__ w, ushort* __restrict__ wp) {
    const int d    = blockIdx.x * 256 + threadIdx.x;
    const int j    = d & 7;
    const int cout = (d >> 3) & 255;
    const int kb8  = d >> 11;
    const int ktap = kb8 >> 5;
    const int cin  = ((kb8 & 31) << 3) | j;
    wp[d] = f2bf(w[cout * (CIN * 9) + cin * 9 + ktap]);
}

// ---- fused deformable-conv GEMM + FULL GroupNorm (cooperative grid sync)
__global__ __launch_bounds__(512, 2)
void dcn_mfma_kernel(const ushort* __restrict__ xn, const float* __restrict__ off,
                     const float* __restrict__ msk, const ushort* __restrict__ wp,
                     const float* __restrict__ gamma, const float* __restrict__ beta,
                     float* __restrict__ out, float* __restrict__ part) {
    __shared__ ushort buf[2][BN * 128];   // 2 x 36.9 KB, swizzled 256B rows
    __shared__ int    s_idx[2][BN][4];    // per-tap coords, slot = tap&1
    __shared__ float  s_wgt[2][BN][4];
    __shared__ float  s_stats[GN_G][2];   // {mean, rsqrt(var+eps)} per group

    const int bid  = blockIdx.x;
    const int swz  = (bid & 7) * (NWG / 8) + (bid >> 3);   // XCD-contiguous chunks
    const int b    = swz / NPB;
    const int pblk = swz - b * NPB;
    const int p0   = pblk * BN;

    const int t    = threadIdx.x;
    const int lane = t & 63;
    const int wid  = t >> 6;              // 0..7

    // ---- coords for one tap, computed by t<144 (one thread per position)
    auto coords = [&](int k) {
        if (t < BN) {
            const int slot = k & 1;
            const int pos  = p0 + t;
            const int hh   = pos / WW;
            const int ww   = pos - hh * WW;
            const size_t obase = ((size_t)b * 18 + 2 * k) * HWSZ + pos;
            const float oy = off[obase];
            const float ox = off[obase + HWSZ];
            const float m  = msk[((size_t)b * 9 + k) * HWSZ + pos];
            const float py = (float)(hh + k / 3 - 1) + oy;
            const float px = (float)(ww + k % 3 - 1) + ox;
            const float y0 = floorf(py), x0 = floorf(px);
            #pragma unroll
            for (int dy = 0; dy < 2; ++dy)
                #pragma unroll
                for (int dx = 0; dx < 2; ++dx) {
                    const float yy = y0 + (float)dy, xx = x0 + (float)dx;
                    const float wb = (1.f - fabsf(py - yy)) * (1.f - fabsf(px - xx));
                    const bool valid = (yy >= 0.f) && (yy < (float)HH) && (xx >= 0.f) && (xx < (float)WW);
                    int yi = (int)yy; yi = yi < 0 ? 0 : (yi > HH - 1 ? HH - 1 : yi);
                    int xi = (int)xx; xi = xi < 0 ? 0 : (xi > WW - 1 ? WW - 1 : xi);
                    s_idx[slot][t][dy * 2 + dx] = yi * WW + xi;
                    s_wgt[slot][t][dy * 2 + dx] = valid ? wb * m : 0.f;
                }
        }
    };

    // staging one half-tap (128 ch): 16-lane group per position (R7-verified geometry)
    const int sp  = lane >> 4;            // 0..3
    const int c16 = lane & 15;
    auto stage = [&](int c, ushort* dstbuf) {
        const int tap  = c >> 1;
        const int half = c & 1;
        const int slot = tap & 1;
        const ushort* xb = xn + (size_t)b * HWSZ * CIN + half * 128 + c16 * 8;
        #pragma unroll
        for (int g = 0; g < 5; ++g) {
            const bool active = (g < 4) || (sp < 2);
            const int p = wid * 18 + ((g < 4) ? (g * 4 + sp) : (16 + sp));
            if (active) {
                float vacc[8] = {0.f, 0.f, 0.f, 0.f, 0.f, 0.f, 0.f, 0.f};
                #pragma unroll
                for (int cr = 0; cr < 4; ++cr) {
                    const int   ix = s_idx[slot][p][cr];
                    const float w  = s_wgt[slot][p][cr];
                    const ushort8 v = *(const ushort8*)(xb + (size_t)ix * CIN);
                    #pragma unroll
                    for (int j = 0; j < 8; ++j)
                        vacc[j] += w * bf2f(v[j]);
                }
                ushort8 o;
                #pragma unroll
                for (int j = 0; j < 8; j += 2) {      // pair casts -> v_cvt_pk_bf16_f32
                    const __hip_bfloat162 h2 = __float22bfloat162_rn(float2{vacc[j], vacc[j + 1]});
                    const uint32_t u = *reinterpret_cast<const uint32_t*>(&h2);
                    o[j]     = (ushort)u;
                    o[j + 1] = (ushort)(u >> 16);
                }
                char* drow = (char*)dstbuf + p * 256;
                *(ushort8*)(drow + ((c16 * 16) ^ ((p & 15) << 4))) = o;
            }
        }
    };

    f32x4 acc[2][9];
    #pragma unroll
    for (int i = 0; i < 2; ++i)
        #pragma unroll
        for (int j = 0; j < 9; ++j)
            acc[i][j] = (f32x4){0.f, 0.f, 0.f, 0.f};

    const int arow = lane & 15;
    const int akb  = lane >> 4;

    // A loads: wave wid owns couts [wid*32, wid*32+32)
    auto loadA = [&](int kb8base, int ks, short8 af[2]) {
        const ushort* wrow = wp + ((size_t)(kb8base + ks * 4 + akb) * COUT + wid * 32 + arow) * 8;
        #pragma unroll
        for (int mt = 0; mt < 2; ++mt)
            af[mt] = *(const short8*)(wrow + mt * 16 * 8);
    };

    auto mfma_chunk = [&](int kb8base, const ushort* src, short8 afA[2]) {
        const char* srow = (const char*)src;
        short8 afB[2];
        #pragma unroll
        for (int ks = 0; ks < 4; ++ks) {
            if (ks < 3) loadA(kb8base, ks + 1, (ks & 1) ? afA : afB);
            short8* afc = (ks & 1) ? afB : afA;
            #pragma unroll
            for (int nt = 0; nt < 9; ++nt) {
                const int row = arow + nt * 16;
                const short8 bfr = *(const short8*)(srow + row * 256 + ((ks * 64 + akb * 16) ^ ((row & 15) << 4)));
                #pragma unroll
                for (int mt = 0; mt < 2; ++mt)
                    acc[mt][nt] = __builtin_amdgcn_mfma_f32_16x16x32_bf16(
                        afc[mt], bfr, acc[mt][nt], 0, 0, 0);
            }
        }
    };

    // ---- RACE-FREE pipeline (R10/R12-verified region pattern)
    coords(0);
    __syncthreads();
    stage(0, buf[0]);
    __syncthreads();                      // publish buf[0]
    for (int c = 0; c < 18; ++c) {
        if (c < 17) stage(c + 1, buf[(c + 1) & 1]);
        if (!(c & 1) && (c >> 1) + 1 < 9) coords((c >> 1) + 1);
        short8 afA[2];
        loadA(c * 16, 0, afA);            // first-A preload
        mfma_chunk(c * 16, buf[c & 1], afA);
        __syncthreads();
    }

    // ---- GN partial stats: wave wid's mt-subtile is exactly group wid*2+mt
    #pragma unroll
    for (int mt = 0; mt < 2; ++mt) {
        float s = 0.f, q = 0.f;
        #pragma unroll
        for (int nt = 0; nt < 9; ++nt)
            #pragma unroll
            for (int r = 0; r < 4; ++r) {
                const float v = acc[mt][nt][r];
                s += v; q += v * v;
            }
        #pragma unroll
        for (int o = 32; o > 0; o >>= 1) {
            s += __shfl_xor(s, o);
            q += __shfl_xor(q, o);
        }
        if (lane == 0) {
            const int bg = b * GN_G + wid * 2 + mt;
            part[((size_t)bg * NPB + pblk) * 2]     = s;
            part[((size_t)bg * NPB + pblk) * 2 + 1] = q;
        }
    }

    // ---- grid-wide sync, then stats reduce (wave w -> groups w, w+8 of batch b)
    __threadfence();
    cg::this_grid().sync();

    for (int g = wid; g < GN_G; g += 8) {
        const float* pg = part + ((size_t)(b * GN_G + g) * NPB + lane) * 2;  // NPB==64
        float s = pg[0];
        float q = pg[1];
        #pragma unroll
        for (int o = 32; o > 0; o >>= 1) {
            s += __shfl_xor(s, o);
            q += __shfl_xor(q, o);
        }
        if (lane == 0) {
            const float invn = 1.f / (float)((COUT / GN_G) * HWSZ);
            const float mean = s * invn;
            const float var  = q * invn - mean * mean;
            s_stats[g][0] = mean;
            s_stats[g][1] = rsqrtf(var + EPSV);
        }
    }
    __syncthreads();

    // ---- normalized epilogue write (single output pass)
    const int prow = lane & 15;
    const int crow = (lane >> 4) * 4;
    #pragma unroll
    for (int mt = 0; mt < 2; ++mt) {
        const int cout = wid * 32 + mt * 16 + crow;
        const int g    = wid * 2 + mt;
        const float mean = s_stats[g][0];
        const float inv  = s_stats[g][1];
        float sc[4], sh[4];
        #pragma unroll
        for (int r = 0; r < 4; ++r) {
            sc[r] = inv * gamma[cout + r];
            sh[r] = beta[cout + r] - mean * sc[r];
        }
        #pragma unroll
        for (int nt = 0; nt < 9; ++nt) {
            const int opos = p0 + nt * 16 + prow;
            float* op = out + ((size_t)b * COUT + cout) * HWSZ + opos;
            #pragma unroll
            for (int r = 0; r < 4; ++r)
                op[(size_t)r * HWSZ] = acc[mt][nt][r] * sc[r] + sh[r];
        }
    }
}

extern "C" void kernel_launch(void* const* d_in, const int* in_sizes, int n_in,
                              void* d_out, int out_size, void* d_ws, size_t ws_size,
                              hipStream_t stream) {
    const float* x      = (const float*)d_in[0];
    const float* offset = (const float*)d_in[1];
    const float* mask   = (const float*)d_in[2];
    const float* weight = (const float*)d_in[3];
    const float* gamma  = (const float*)d_in[4];
    const float* beta   = (const float*)d_in[5];
    float* out = (float*)d_out;

    // ws: xn bf16 (18.9 MB) | wp bf16 (1.18 MB) | part (32 KB)
    ushort* xn   = (ushort*)d_ws;
    ushort* wp   = xn + (size_t)BATCH * HWSZ * CIN;
    float*  part = (float*)(wp + (size_t)9 * CIN * COUT);

    {
        dim3 g(HWSZ / 64, CIN / 64, BATCH);
        nhwc_kernel<<<g, 256, 0, stream>>>(x, xn);
    }
    repack_w_kernel<<<9 * CIN * COUT / 256, 256, 0, stream>>>(weight, wp);

    void* args[] = {(void*)&xn, (void*)&offset, (void*)&mask, (void*)&wp,
                    (void*)&gamma, (void*)&beta, (void*)&out, (void*)&part};
    hipLaunchCooperativeKernel((void*)dcn_mfma_kernel, dim3(NWG), dim3(512),
                               args, 0, stream);
}

// Round 14
// 104.983 us; speedup vs baseline: 1.5019x; 1.5019x over previous
//
#include <hip/hip_runtime.h>
#include <hip/hip_bf16.h>
#include <cstdint>

typedef short  short8  __attribute__((ext_vector_type(8)));
typedef ushort ushort8 __attribute__((ext_vector_type(8)));
typedef float  f32x4   __attribute__((ext_vector_type(4)));

#define BATCH 4
#define CIN   256
#define COUT  256
#define HH    96
#define WW    96
#define HWSZ  9216
#define GN_G  16
#define EPSV  1e-5f
#define BN    144           // positions per block
#define NPB   64            // position-blocks per batch (9216/144)
#define NWG   (BATCH*NPB)   // 256 blocks = exactly 1/CU, %8==0 -> bijective XCD swizzle

__device__ __forceinline__ float bf2f(ushort u) {
    return __uint_as_float(((uint32_t)u) << 16);
}
__device__ __forceinline__ ushort f2bf(float f) {
    uint32_t u = __float_as_uint(f);
    u += 0x7FFFu + ((u >> 16) & 1u);   // round-to-nearest-even
    return (ushort)(u >> 16);
}

// ---- x: [b][c][p] fp32 -> xn: [b][p][c] bf16 (tiled transpose via LDS)
__global__ __launch_bounds__(256)
void nhwc_kernel(const float* __restrict__ x, ushort* __restrict__ xn) {
    __shared__ ushort tile[64][66];
    const int b  = blockIdx.z;
    const int cb = blockIdx.y * 64;
    const int pb = blockIdx.x * 64;
    const int t  = threadIdx.x;
    {
        const int pl = t & 63;
        const int cq = t >> 6;
        #pragma unroll
        for (int i = 0; i < 16; ++i) {
            const int c = cq * 16 + i;
            tile[c][pl] = f2bf(x[((size_t)b * CIN + cb + c) * HWSZ + pb + pl]);
        }
    }
    __syncthreads();
    {
        const int cl = t & 63;
        const int pq = t >> 6;
        #pragma unroll
        for (int i = 0; i < 16; ++i) {
            const int p = pq * 16 + i;
            xn[((size_t)b * HWSZ + pb + p) * CIN + cb + cl] = tile[cl][p];
        }
    }
}

// ---- weight [cout][cin][3][3] fp32 -> Wp[kb8][cout][8] bf16, globalK = tap*256 + cin
__global__ __launch_bounds__(256)
void repack_w_kernel(const float* __restrict__ w, ushort* __restrict__ wp) {
    const int d    = blockIdx.x * 256 + threadIdx.x;
    const int j    = d & 7;
    const int cout = (d >> 3) & 255;
    const int kb8  = d >> 11;
    const int ktap = kb8 >> 5;
    const int cin  = ((kb8 & 31) << 3) | j;
    wp[d] = f2bf(w[cout * (CIN * 9) + cin * 9 + ktap]);
}

// ---- fused deformable-conv GEMM + GN partial stats
//      BN=144, 256 blocks (1/CU), 8 waves = 4 cout-groups x 2 K-halves (K-split)
__global__ __launch_bounds__(512, 2)
void dcn_mfma_kernel(const ushort* __restrict__ xn, const float* __restrict__ off,
                     const float* __restrict__ msk, const ushort* __restrict__ wp,
                     float* __restrict__ out, float* __restrict__ part) {
    __shared__ __align__(16) ushort buf[2][BN * 128];   // 2 x 36.9 KB, swizzled 256B rows
    __shared__ int    s_idx[2][BN][4];    // per-tap coords, slot = tap&1
    __shared__ float  s_wgt[2][BN][4];

    const int bid  = blockIdx.x;
    const int swz  = (bid & 7) * (NWG / 8) + (bid >> 3);   // XCD-contiguous chunks
    const int b    = swz / NPB;
    const int pblk = swz - b * NPB;
    const int p0   = pblk * BN;

    const int t    = threadIdx.x;
    const int lane = t & 63;
    const int wid  = t >> 6;              // 0..7
    const int cg   = wid & 3;             // cout group: couts [cg*64, cg*64+64)
    const int kh   = wid >> 2;            // K-half: ks in {2kh, 2kh+1}

    // ---- coords for one tap, computed by t<144 (one thread per position)
    auto coords = [&](int k) {
        if (t < BN) {
            const int slot = k & 1;
            const int pos  = p0 + t;
            const int hh   = pos / WW;
            const int ww   = pos - hh * WW;
            const size_t obase = ((size_t)b * 18 + 2 * k) * HWSZ + pos;
            const float oy = off[obase];
            const float ox = off[obase + HWSZ];
            const float m  = msk[((size_t)b * 9 + k) * HWSZ + pos];
            const float py = (float)(hh + k / 3 - 1) + oy;
            const float px = (float)(ww + k % 3 - 1) + ox;
            const float y0 = floorf(py), x0 = floorf(px);
            #pragma unroll
            for (int dy = 0; dy < 2; ++dy)
                #pragma unroll
                for (int dx = 0; dx < 2; ++dx) {
                    const float yy = y0 + (float)dy, xx = x0 + (float)dx;
                    const float wb = (1.f - fabsf(py - yy)) * (1.f - fabsf(px - xx));
                    const bool valid = (yy >= 0.f) && (yy < (float)HH) && (xx >= 0.f) && (xx < (float)WW);
                    int yi = (int)yy; yi = yi < 0 ? 0 : (yi > HH - 1 ? HH - 1 : yi);
                    int xi = (int)xx; xi = xi < 0 ? 0 : (xi > WW - 1 ? WW - 1 : xi);
                    s_idx[slot][t][dy * 2 + dx] = yi * WW + xi;
                    s_wgt[slot][t][dy * 2 + dx] = valid ? wb * m : 0.f;
                }
        }
    };

    // staging one half-tap (128 ch): 16-lane group per position (R7-verified geometry)
    const int sp  = lane >> 4;            // 0..3
    const int c16 = lane & 15;
    auto stage = [&](int c, ushort* dstbuf) {
        const int tap  = c >> 1;
        const int half = c & 1;
        const int slot = tap & 1;
        const ushort* xb = xn + (size_t)b * HWSZ * CIN + half * 128 + c16 * 8;
        #pragma unroll
        for (int g = 0; g < 5; ++g) {
            const bool active = (g < 4) || (sp < 2);
            const int p = wid * 18 + ((g < 4) ? (g * 4 + sp) : (16 + sp));
            if (active) {
                float vacc[8] = {0.f, 0.f, 0.f, 0.f, 0.f, 0.f, 0.f, 0.f};
                #pragma unroll
                for (int cr = 0; cr < 4; ++cr) {
                    const int   ix = s_idx[slot][p][cr];
                    const float w  = s_wgt[slot][p][cr];
                    const ushort8 v = *(const ushort8*)(xb + (size_t)ix * CIN);
                    #pragma unroll
                    for (int j = 0; j < 8; ++j)
                        vacc[j] += w * bf2f(v[j]);
                }
                ushort8 o;
                #pragma unroll
                for (int j = 0; j < 8; j += 2) {      // pair casts -> v_cvt_pk_bf16_f32
                    const __hip_bfloat162 h2 = __float22bfloat162_rn(float2{vacc[j], vacc[j + 1]});
                    const uint32_t u = *reinterpret_cast<const uint32_t*>(&h2);
                    o[j]     = (ushort)u;
                    o[j + 1] = (ushort)(u >> 16);
                }
                char* drow = (char*)dstbuf + p * 256;
                *(ushort8*)(drow + ((c16 * 16) ^ ((p & 15) << 4))) = o;
            }
        }
    };

    f32x4 acc[4][9];
    #pragma unroll
    for (int i = 0; i < 4; ++i)
        #pragma unroll
        for (int j = 0; j < 9; ++j)
            acc[i][j] = (f32x4){0.f, 0.f, 0.f, 0.f};

    const int arow = lane & 15;
    const int akb  = lane >> 4;

    // A loads: cout group cg, 4 mt tiles of 16
    auto loadA = [&](int kb8base, int ks, short8 af[4]) {
        const ushort* wrow = wp + ((size_t)(kb8base + ks * 4 + akb) * COUT + cg * 64 + arow) * 8;
        #pragma unroll
        for (int mt = 0; mt < 4; ++mt)
            af[mt] = *(const short8*)(wrow + mt * 16 * 8);
    };

    // MFMA over this wave's K-half of one chunk (2 of 4 ks-steps)
    auto mfma_chunk = [&](int kb8base, const ushort* src, short8 afA[4]) {
        const char* srow = (const char*)src;
        short8 afB[4];
        #pragma unroll
        for (int ks = 0; ks < 2; ++ks) {
            const int ksg = kh * 2 + ks;
            if (ks == 0) loadA(kb8base, kh * 2 + 1, afB);
            short8* afc = ks ? afB : afA;
            #pragma unroll
            for (int nt = 0; nt < 9; ++nt) {
                const int row = arow + nt * 16;
                const short8 bfr = *(const short8*)(srow + row * 256 + ((ksg * 64 + akb * 16) ^ ((row & 15) << 4)));
                #pragma unroll
                for (int mt = 0; mt < 4; ++mt)
                    acc[mt][nt] = __builtin_amdgcn_mfma_f32_16x16x32_bf16(
                        afc[mt], bfr, acc[mt][nt], 0, 0, 0);
            }
        }
    };

    // ---- RACE-FREE pipeline (R10/R12-verified region pattern)
    coords(0);
    __syncthreads();
    stage(0, buf[0]);
    __syncthreads();                      // publish buf[0]
    for (int c = 0; c < 18; ++c) {
        if (c < 17) stage(c + 1, buf[(c + 1) & 1]);
        if (!(c & 1) && (c >> 1) + 1 < 9) coords((c >> 1) + 1);
        short8 afA[4];
        loadA(c * 16, kh * 2, afA);       // first-A preload for this wave's K-half
        mfma_chunk(c * 16, buf[c & 1], afA);
        __syncthreads();
    }

    // ---- K-split reduction: waves 4-7 ship partial acc to partners 0-3 via LDS
    // scratch: [256 planes][10 f32x4] rows (stride 10 -> 2-way banks, free); 40.9 KB <= buf
    {
        f32x4* s_xch = reinterpret_cast<f32x4*>(&buf[0][0]);
        const int plane = cg * 64 + lane;
        #pragma unroll
        for (int mt = 0; mt < 4; ++mt) {
            if (wid >= 4) {
                #pragma unroll
                for (int nt = 0; nt < 9; ++nt)
                    s_xch[plane * 10 + nt] = acc[mt][nt];
            }
            __syncthreads();
            if (wid < 4) {
                #pragma unroll
                for (int nt = 0; nt < 9; ++nt)
                    acc[mt][nt] += s_xch[plane * 10 + nt];
            }
            __syncthreads();
        }
    }

    if (wid < 4) {
        // ---- epilogue: C/D layout col=lane&15 (pos), row=(lane>>4)*4+r (cout)
        const int prow = lane & 15;
        const int crow = (lane >> 4) * 4;
        #pragma unroll
        for (int mt = 0; mt < 4; ++mt) {
            const int cout = cg * 64 + mt * 16 + crow;
            #pragma unroll
            for (int nt = 0; nt < 9; ++nt) {
                const int opos = p0 + nt * 16 + prow;
                float* op = out + ((size_t)b * COUT + cout) * HWSZ + opos;
                #pragma unroll
                for (int r = 0; r < 4; ++r)
                    op[(size_t)r * HWSZ] = acc[mt][nt][r];
            }
        }

        // ---- GN partial stats: group of cout tile mt is cg*4+mt
        #pragma unroll
        for (int mt = 0; mt < 4; ++mt) {
            float s = 0.f, q = 0.f;
            #pragma unroll
            for (int nt = 0; nt < 9; ++nt)
                #pragma unroll
                for (int r = 0; r < 4; ++r) {
                    const float v = acc[mt][nt][r];
                    s += v; q += v * v;
                }
            #pragma unroll
            for (int o = 32; o > 0; o >>= 1) {
                s += __shfl_xor(s, o);
                q += __shfl_xor(q, o);
            }
            if (lane == 0) {
                const int bg = b * GN_G + cg * 4 + mt;
                part[((size_t)bg * NPB + pblk) * 2]     = s;
                part[((size_t)bg * NPB + pblk) * 2 + 1] = q;
            }
        }
    }
}

// ---- reduce partials -> stats[bg] = {mean, var}; 256 threads, 4 per bg
__global__ void gn_final_kernel(const float* __restrict__ part, float* __restrict__ stats) {
    const int t  = threadIdx.x;
    const int bg = t >> 2;
    const int j  = t & 3;
    float s = 0.f, q = 0.f;
    for (int i = j; i < NPB; i += 4) {
        s += part[((size_t)bg * NPB + i) * 2];
        q += part[((size_t)bg * NPB + i) * 2 + 1];
    }
    s += __shfl_xor(s, 1); q += __shfl_xor(q, 1);
    s += __shfl_xor(s, 2); q += __shfl_xor(q, 2);
    if (j == 0) {
        const float invn = 1.f / (float)((COUT / GN_G) * HWSZ);
        const float mean = s * invn;
        stats[bg * 2]     = mean;
        stats[bg * 2 + 1] = q * invn - mean * mean;
    }
}

// ---- GroupNorm apply (in place)
__global__ __launch_bounds__(256)
void gn_apply_kernel(float* __restrict__ y, const float* __restrict__ stats,
                     const float* __restrict__ gamma, const float* __restrict__ beta) {
    const int i = blockIdx.x * 256 + threadIdx.x;       // float4 index
    const int e = i * 4;
    const int c  = (e / HWSZ) & (COUT - 1);
    const int bg = e / (HWSZ * (COUT / GN_G));
    const float mean = stats[bg * 2];
    const float var  = stats[bg * 2 + 1];
    const float inv  = rsqrtf(var + EPSV);
    const float sc = inv * gamma[c];
    const float sh = beta[c] - mean * sc;
    float4 v = ((float4*)y)[i];
    v.x = v.x * sc + sh;
    v.y = v.y * sc + sh;
    v.z = v.z * sc + sh;
    v.w = v.w * sc + sh;
    ((float4*)y)[i] = v;
}

extern "C" void kernel_launch(void* const* d_in, const int* in_sizes, int n_in,
                              void* d_out, int out_size, void* d_ws, size_t ws_size,
                              hipStream_t stream) {
    const float* x      = (const float*)d_in[0];
    const float* offset = (const float*)d_in[1];
    const float* mask   = (const float*)d_in[2];
    const float* weight = (const float*)d_in[3];
    const float* gamma  = (const float*)d_in[4];
    const float* beta   = (const float*)d_in[5];
    float* out = (float*)d_out;

    // ws: xn bf16 (18.9 MB) | wp bf16 (1.18 MB) | part (32 KB) | stats (512 B)
    ushort* xn    = (ushort*)d_ws;
    ushort* wp    = xn + (size_t)BATCH * HWSZ * CIN;
    float*  part  = (float*)(wp + (size_t)9 * CIN * COUT);
    float*  stats = part + (size_t)BATCH * GN_G * NPB * 2;

    {
        dim3 g(HWSZ / 64, CIN / 64, BATCH);
        nhwc_kernel<<<g, 256, 0, stream>>>(x, xn);
    }
    repack_w_kernel<<<9 * CIN * COUT / 256, 256, 0, stream>>>(weight, wp);

    dcn_mfma_kernel<<<NWG, 512, 0, stream>>>(xn, offset, mask, wp, out, part);

    gn_final_kernel<<<1, 256, 0, stream>>>(part, stats);
    gn_apply_kernel<<<(size_t)BATCH * COUT * HWSZ / 4 / 256, 256, 0, stream>>>(out, stats, gamma, beta);
}

// Round 16
// 95.499 us; speedup vs baseline: 1.6511x; 1.0993x over previous
//
#include <hip/hip_runtime.h>
#include <hip/hip_bf16.h>
#include <cstdint>

typedef short    short8  __attribute__((ext_vector_type(8)));
typedef ushort   ushort8 __attribute__((ext_vector_type(8)));
typedef float    f32x4   __attribute__((ext_vector_type(4)));
typedef _Float16 half8   __attribute__((ext_vector_type(8)));

#define BATCH 4
#define CIN   256
#define COUT  256
#define HH    96
#define WW    96
#define HWSZ  9216
#define GN_G  16
#define EPSV  1e-5f
#define BN    144           // positions per block
#define NPB   64            // position-blocks per batch (9216/144)
#define NWG   (BATCH*NPB)   // 256 blocks = exactly 1/CU, %8==0 -> bijective XCD swizzle

__device__ __forceinline__ float bf2f(ushort u) {
    return __uint_as_float(((uint32_t)u) << 16);
}
__device__ __forceinline__ ushort f2bf(float f) {
    uint32_t u = __float_as_uint(f);
    u += 0x7FFFu + ((u >> 16) & 1u);   // round-to-nearest-even
    return (ushort)(u >> 16);
}

// ---- x: [b][c][p] fp32 -> xn: [b][p][c] f16 (tiled transpose via LDS)
__global__ __launch_bounds__(256)
void nhwc_kernel(const float* __restrict__ x, _Float16* __restrict__ xn) {
    __shared__ _Float16 tile[64][66];
    const int b  = blockIdx.z;
    const int cb = blockIdx.y * 64;
    const int pb = blockIdx.x * 64;
    const int t  = threadIdx.x;
    {
        const int pl = t & 63;
        const int cq = t >> 6;
        #pragma unroll
        for (int i = 0; i < 16; ++i) {
            const int c = cq * 16 + i;
            tile[c][pl] = (_Float16)x[((size_t)b * CIN + cb + c) * HWSZ + pb + pl];
        }
    }
    __syncthreads();
    {
        const int cl = t & 63;
        const int pq = t >> 6;
        #pragma unroll
        for (int i = 0; i < 16; ++i) {
            const int p = pq * 16 + i;
            xn[((size_t)b * HWSZ + pb + p) * CIN + cb + cl] = tile[cl][p];
        }
    }
}

// ---- weight [cout][cin][3][3] fp32 -> Wp[kb8][cout][8] bf16, globalK = tap*256 + cin
__global__ __launch_bounds__(256)
void repack_w_kernel(const float* __restrict__ w, ushort* __restrict__ wp) {
    const int d    = blockIdx.x * 256 + threadIdx.x;
    const int j    = d & 7;
    const int cout = (d >> 3) & 255;
    const int kb8  = d >> 11;
    const int ktap = kb8 >> 5;
    const int cin  = ((kb8 & 31) << 3) | j;
    wp[d] = f2bf(w[cout * (CIN * 9) + cin * 9 + ktap]);
}

// ---- fused deformable-conv GEMM + GN partial stats
//      BN=144, 256 blocks (1/CU), 8 waves = 4 cout-groups x 2 K-halves (K-split)
//      f16 gather+combine (v_pk_fma_f16), bf16 MFMA (verified layout)
__global__ __launch_bounds__(512, 2)
void dcn_mfma_kernel(const _Float16* __restrict__ xn, const float* __restrict__ off,
                     const float* __restrict__ msk, const ushort* __restrict__ wp,
                     float* __restrict__ out, ushort* __restrict__ yb, int use_bf16,
                     float* __restrict__ part) {
    __shared__ __align__(16) ushort buf[2][BN * 128];   // 2 x 36.9 KB, swizzled 256B rows
    __shared__ int    s_idx[2][BN][4];    // per-tap coords, slot = tap&1
    __shared__ float  s_wgt[2][BN][4];

    const int bid  = blockIdx.x;
    const int swz  = (bid & 7) * (NWG / 8) + (bid >> 3);   // XCD-contiguous chunks
    const int b    = swz / NPB;
    const int pblk = swz - b * NPB;
    const int p0   = pblk * BN;

    const int t    = threadIdx.x;
    const int lane = t & 63;
    const int wid  = t >> 6;              // 0..7
    const int cgp  = wid & 3;             // cout group: couts [cgp*64, cgp*64+64)
    const int kh   = wid >> 2;            // K-half: ks in {2kh, 2kh+1}

    // ---- coords for one tap, computed by t<144 (one thread per position)
    auto coords = [&](int k) {
        if (t < BN) {
            const int slot = k & 1;
            const int pos  = p0 + t;
            const int hh   = pos / WW;
            const int ww   = pos - hh * WW;
            const size_t obase = ((size_t)b * 18 + 2 * k) * HWSZ + pos;
            const float oy = off[obase];
            const float ox = off[obase + HWSZ];
            const float m  = msk[((size_t)b * 9 + k) * HWSZ + pos];
            const float py = (float)(hh + k / 3 - 1) + oy;
            const float px = (float)(ww + k % 3 - 1) + ox;
            const float y0 = floorf(py), x0 = floorf(px);
            #pragma unroll
            for (int dy = 0; dy < 2; ++dy)
                #pragma unroll
                for (int dx = 0; dx < 2; ++dx) {
                    const float yy = y0 + (float)dy, xx = x0 + (float)dx;
                    const float wb = (1.f - fabsf(py - yy)) * (1.f - fabsf(px - xx));
                    const bool valid = (yy >= 0.f) && (yy < (float)HH) && (xx >= 0.f) && (xx < (float)WW);
                    int yi = (int)yy; yi = yi < 0 ? 0 : (yi > HH - 1 ? HH - 1 : yi);
                    int xi = (int)xx; xi = xi < 0 ? 0 : (xi > WW - 1 ? WW - 1 : xi);
                    s_idx[slot][t][dy * 2 + dx] = yi * WW + xi;
                    s_wgt[slot][t][dy * 2 + dx] = valid ? wb * m : 0.f;
                }
        }
    };

    // staging one half-tap (128 ch), f16 packed combine (R7-verified gather geometry)
    const int sp  = lane >> 4;            // 0..3
    const int c16 = lane & 15;
    auto stage = [&](int c, ushort* dstbuf) {
        const int tap  = c >> 1;
        const int half = c & 1;
        const int slot = tap & 1;
        const _Float16* xb = xn + (size_t)b * HWSZ * CIN + half * 128 + c16 * 8;
        #pragma unroll
        for (int g = 0; g < 5; ++g) {
            const bool active = (g < 4) || (sp < 2);
            const int p = wid * 18 + ((g < 4) ? (g * 4 + sp) : (16 + sp));
            if (active) {
                const _Float16 w0 = (_Float16)s_wgt[slot][p][0];
                const _Float16 w1 = (_Float16)s_wgt[slot][p][1];
                const _Float16 w2 = (_Float16)s_wgt[slot][p][2];
                const _Float16 w3 = (_Float16)s_wgt[slot][p][3];
                const half8 v0 = *(const half8*)(xb + (size_t)s_idx[slot][p][0] * CIN);
                const half8 v1 = *(const half8*)(xb + (size_t)s_idx[slot][p][1] * CIN);
                const half8 v2 = *(const half8*)(xb + (size_t)s_idx[slot][p][2] * CIN);
                const half8 v3 = *(const half8*)(xb + (size_t)s_idx[slot][p][3] * CIN);
                const half8 h = v0 * w0 + v1 * w1 + v2 * w2 + v3 * w3;  // v_pk_fma_f16
                ushort8 o;
                #pragma unroll
                for (int j = 0; j < 8; j += 2) {     // f16 -> f32 -> packed bf16
                    const __hip_bfloat162 h2 =
                        __float22bfloat162_rn(float2{(float)h[j], (float)h[j + 1]});
                    const uint32_t u = *reinterpret_cast<const uint32_t*>(&h2);
                    o[j]     = (ushort)u;
                    o[j + 1] = (ushort)(u >> 16);
                }
                char* drow = (char*)dstbuf + p * 256;
                *(ushort8*)(drow + ((c16 * 16) ^ ((p & 15) << 4))) = o;
            }
        }
    };

    f32x4 acc[4][9];
    #pragma unroll
    for (int i = 0; i < 4; ++i)
        #pragma unroll
        for (int j = 0; j < 9; ++j)
            acc[i][j] = (f32x4){0.f, 0.f, 0.f, 0.f};

    const int arow = lane & 15;
    const int akb  = lane >> 4;

    // A loads: cout group cgp, 4 mt tiles of 16
    auto loadA = [&](int kb8base, int ks, short8 af[4]) {
        const ushort* wrow = wp + ((size_t)(kb8base + ks * 4 + akb) * COUT + cgp * 64 + arow) * 8;
        #pragma unroll
        for (int mt = 0; mt < 4; ++mt)
            af[mt] = *(const short8*)(wrow + mt * 16 * 8);
    };

    // MFMA over this wave's K-half of one chunk (2 of 4 ks-steps)
    auto mfma_chunk = [&](int kb8base, const ushort* src, short8 afA[4]) {
        const char* srow = (const char*)src;
        short8 afB[4];
        #pragma unroll
        for (int ks = 0; ks < 2; ++ks) {
            const int ksg = kh * 2 + ks;
            if (ks == 0) loadA(kb8base, kh * 2 + 1, afB);
            short8* afc = ks ? afB : afA;
            #pragma unroll
            for (int nt = 0; nt < 9; ++nt) {
                const int row = arow + nt * 16;
                const short8 bfr = *(const short8*)(srow + row * 256 + ((ksg * 64 + akb * 16) ^ ((row & 15) << 4)));
                #pragma unroll
                for (int mt = 0; mt < 4; ++mt)
                    acc[mt][nt] = __builtin_amdgcn_mfma_f32_16x16x32_bf16(
                        afc[mt], bfr, acc[mt][nt], 0, 0, 0);
            }
        }
    };

    // ---- RACE-FREE pipeline (R10/R12-verified region pattern)
    coords(0);
    __syncthreads();
    stage(0, buf[0]);
    __syncthreads();                      // publish buf[0]
    for (int c = 0; c < 18; ++c) {
        if (c < 17) stage(c + 1, buf[(c + 1) & 1]);
        if (!(c & 1) && (c >> 1) + 1 < 9) coords((c >> 1) + 1);
        short8 afA[4];
        loadA(c * 16, kh * 2, afA);       // first-A preload for this wave's K-half
        mfma_chunk(c * 16, buf[c & 1], afA);
        __syncthreads();
    }

    // ---- K-split reduction: waves 4-7 ship partial acc to partners 0-3 via LDS
    {
        f32x4* s_xch = reinterpret_cast<f32x4*>(&buf[0][0]);
        const int plane = cgp * 64 + lane;
        #pragma unroll
        for (int mt = 0; mt < 4; ++mt) {
            if (wid >= 4) {
                #pragma unroll
                for (int nt = 0; nt < 9; ++nt)
                    s_xch[plane * 10 + nt] = acc[mt][nt];
            }
            __syncthreads();
            if (wid < 4) {
                #pragma unroll
                for (int nt = 0; nt < 9; ++nt)
                    acc[mt][nt] += s_xch[plane * 10 + nt];
            }
            __syncthreads();
        }
    }

    if (wid < 4) {
        // ---- epilogue: C/D layout col=lane&15 (pos), row=(lane>>4)*4+r (cout)
        const int prow = lane & 15;
        const int crow = (lane >> 4) * 4;
        if (use_bf16) {
            #pragma unroll
            for (int mt = 0; mt < 4; ++mt) {
                const int cout = cgp * 64 + mt * 16 + crow;
                #pragma unroll
                for (int nt = 0; nt < 9; ++nt) {
                    const int opos = p0 + nt * 16 + prow;
                    ushort* op = yb + ((size_t)b * COUT + cout) * HWSZ + opos;
                    #pragma unroll
                    for (int r = 0; r < 4; ++r)
                        op[(size_t)r * HWSZ] = f2bf(acc[mt][nt][r]);
                }
            }
        } else {
            #pragma unroll
            for (int mt = 0; mt < 4; ++mt) {
                const int cout = cgp * 64 + mt * 16 + crow;
                #pragma unroll
                for (int nt = 0; nt < 9; ++nt) {
                    const int opos = p0 + nt * 16 + prow;
                    float* op = out + ((size_t)b * COUT + cout) * HWSZ + opos;
                    #pragma unroll
                    for (int r = 0; r < 4; ++r)
                        op[(size_t)r * HWSZ] = acc[mt][nt][r];
                }
            }
        }

        // ---- GN partial stats: group of cout tile mt is cgp*4+mt
        #pragma unroll
        for (int mt = 0; mt < 4; ++mt) {
            float s = 0.f, q = 0.f;
            #pragma unroll
            for (int nt = 0; nt < 9; ++nt)
                #pragma unroll
                for (int r = 0; r < 4; ++r) {
                    const float v = acc[mt][nt][r];
                    s += v; q += v * v;
                }
            #pragma unroll
            for (int o = 32; o > 0; o >>= 1) {
                s += __shfl_xor(s, o);
                q += __shfl_xor(q, o);
            }
            if (lane == 0) {
                const int bg = b * GN_G + cgp * 4 + mt;
                part[((size_t)bg * NPB + pblk) * 2]     = s;
                part[((size_t)bg * NPB + pblk) * 2 + 1] = q;
            }
        }
    }
}

// ---- GN apply from bf16 y (self-reducing stats); grid (9, 64 bg)
// per (b,group): 16ch x 9216 = 147456 el = 9 blocks x 8 it x 256 t x 8 el
__global__ __launch_bounds__(256)
void gn_apply_bf16_kernel(const ushort* __restrict__ yb, const float* __restrict__ part,
                          const float* __restrict__ gamma, const float* __restrict__ beta,
                          float* __restrict__ out) {
    __shared__ float sm[2];
    const int bg = blockIdx.y;
    const int t  = threadIdx.x;
    if (t < 64) {
        float s = part[((size_t)bg * NPB + t) * 2];
        float q = part[((size_t)bg * NPB + t) * 2 + 1];
        #pragma unroll
        for (int o = 32; o > 0; o >>= 1) {
            s += __shfl_xor(s, o);
            q += __shfl_xor(q, o);
        }
        if (t == 0) {
            const float invn = 1.f / (float)((COUT / GN_G) * HWSZ);
            const float mean = s * invn;
            const float var  = q * invn - mean * mean;
            sm[0] = mean;
            sm[1] = rsqrtf(var + EPSV);
        }
    }
    __syncthreads();
    const float mean = sm[0], inv = sm[1];
    const size_t base = (size_t)bg * (COUT / GN_G) * HWSZ + (size_t)blockIdx.x * 16384;
    #pragma unroll 2
    for (int it = 0; it < 8; ++it) {
        const size_t e = base + ((size_t)(it * 256 + t)) * 8;
        const int c = (int)((e / HWSZ) & (COUT - 1));
        const float sc = inv * gamma[c];
        const float sh = beta[c] - mean * sc;
        const ushort8 v = *(const ushort8*)(yb + e);
        float4 o0, o1;
        o0.x = bf2f(v[0]) * sc + sh;  o0.y = bf2f(v[1]) * sc + sh;
        o0.z = bf2f(v[2]) * sc + sh;  o0.w = bf2f(v[3]) * sc + sh;
        o1.x = bf2f(v[4]) * sc + sh;  o1.y = bf2f(v[5]) * sc + sh;
        o1.z = bf2f(v[6]) * sc + sh;  o1.w = bf2f(v[7]) * sc + sh;
        *(float4*)(out + e)     = o0;
        *(float4*)(out + e + 4) = o1;
    }
}

// ---- GN apply fallback, fp32 in place; grid (9, 64 bg): 9 x 16 it x 256 t x 4 el
__global__ __launch_bounds__(256)
void gn_apply_f32_kernel(float* __restrict__ y, const float* __restrict__ part,
                         const float* __restrict__ gamma, const float* __restrict__ beta) {
    __shared__ float sm[2];
    const int bg = blockIdx.y;
    const int t  = threadIdx.x;
    if (t < 64) {
        float s = part[((size_t)bg * NPB + t) * 2];
        float q = part[((size_t)bg * NPB + t) * 2 + 1];
        #pragma unroll
        for (int o = 32; o > 0; o >>= 1) {
            s += __shfl_xor(s, o);
            q += __shfl_xor(q, o);
        }
        if (t == 0) {
            const float invn = 1.f / (float)((COUT / GN_G) * HWSZ);
            const float mean = s * invn;
            const float var  = q * invn - mean * mean;
            sm[0] = mean;
            sm[1] = rsqrtf(var + EPSV);
        }
    }
    __syncthreads();
    const float mean = sm[0], inv = sm[1];
    const size_t base = (size_t)bg * (COUT / GN_G) * HWSZ + (size_t)blockIdx.x * 16384;
    #pragma unroll 2
    for (int it = 0; it < 16; ++it) {
        const size_t e = base + ((size_t)(it * 256 + t)) * 4;
        const int c = (int)((e / HWSZ) & (COUT - 1));
        const float sc = inv * gamma[c];
        const float sh = beta[c] - mean * sc;
        float4 v = *(float4*)(y + e);
        v.x = v.x * sc + sh;  v.y = v.y * sc + sh;
        v.z = v.z * sc + sh;  v.w = v.w * sc + sh;
        *(float4*)(y + e) = v;
    }
}

extern "C" void kernel_launch(void* const* d_in, const int* in_sizes, int n_in,
                              void* d_out, int out_size, void* d_ws, size_t ws_size,
                              hipStream_t stream) {
    const float* x      = (const float*)d_in[0];
    const float* offset = (const float*)d_in[1];
    const float* mask   = (const float*)d_in[2];
    const float* weight = (const float*)d_in[3];
    const float* gamma  = (const float*)d_in[4];
    const float* beta   = (const float*)d_in[5];
    float* out = (float*)d_out;

    // ws: xn f16 (18.9 MB) | wp bf16 (1.18 MB) | part (32 KB) | yb bf16 (18.9 MB, optional)
    const size_t XN = (size_t)BATCH * HWSZ * CIN;
    const size_t WP = (size_t)9 * CIN * COUT;
    const size_t PT = (size_t)BATCH * GN_G * NPB * 2;
    _Float16* xn   = (_Float16*)d_ws;
    ushort*   wp   = (ushort*)d_ws + XN;
    float*    part = (float*)((ushort*)d_ws + XN + WP);
    ushort*   yb   = (ushort*)(part + PT);
    const size_t need = (XN + WP) * 2 + PT * 4 + (size_t)BATCH * COUT * HWSZ * 2;
    const int use_bf16 = (ws_size >= need) ? 1 : 0;

    {
        dim3 g(HWSZ / 64, CIN / 64, BATCH);
        nhwc_kernel<<<g, 256, 0, stream>>>(x, xn);
    }
    repack_w_kernel<<<9 * CIN * COUT / 256, 256, 0, stream>>>(weight, wp);

    dcn_mfma_kernel<<<NWG, 512, 0, stream>>>(xn, offset, mask, wp, out, yb, use_bf16, part);

    dim3 gg(9, BATCH * GN_G);
    if (use_bf16)
        gn_apply_bf16_kernel<<<gg, 256, 0, stream>>>(yb, part, gamma, beta, out);
    else
        gn_apply_f32_kernel<<<gg, 256, 0, stream>>>(out, part, gamma, beta);
}